// Round 9
// baseline (181.722 us; speedup 1.0000x reference)
//
#include <hip/hip_runtime.h>

// Frames [B, T, C, H, W] = [8, 8, 3, 256, 256] fp32
#define BB 8
#define TT 8
#define HH 256
#define WW 256
#define FRAME_PIX (HH * WW)
#define XW 64                        // tile width
#define RROWS 8                      // tile rows
#define NYT (HH / RROWS)             // 32
#define NXT (WW / XW)                // 4
#define PADW 72                      // 4 pad + 64 + 4 pad floats
#define NBLK (BB * 2 * NYT * NXT)    // 2048 blocks
#define EPS 1e-3f
#define INV_N (1.0f / (float)((size_t)BB * (TT - 1) * 2 * HH * WW))

__device__ __forceinline__ float4 ld4(const float* __restrict__ p) {
    return *reinterpret_cast<const float4*>(p);
}
__device__ __forceinline__ void st4(float* p, const float4 v) {
    *reinterpret_cast<float4*>(p) = v;
}
__device__ __forceinline__ float4 gray4(const float4 r, const float4 g, const float4 b) {
    float4 o;
    o.x = 0.2989f * r.x + 0.587f * g.x + 0.114f * b.x;
    o.y = 0.2989f * r.y + 0.587f * g.y + 0.114f * b.y;
    o.z = 0.2989f * r.z + 0.587f * g.z + 0.114f * b.z;
    o.w = 0.2989f * r.w + 0.587f * g.w + 0.114f * b.w;
    return o;
}

// 128-thread block = 64x8 tile marching over a frame run (half 0: pairs
// 0..3 / frames 0..4; half 1: pairs 4..6 / frames 4..7). 2048 blocks =
// 8 blocks/CU: enough independent load->barrier->compute chains per CU to
// overlap each other's barrier drains (R8 evidence: 4 blocks/CU ran at
// only 2.05 TB/s read, far under the ~2.9 TB/s MSHR wall).
// Frame channels loaded once per block; gray(t+1) computed in regs during
// pair t and rotated into LDS; gt channels carried for motion magnitude.
__global__ __launch_bounds__(128, 8) void flow_loss_kernel(
    const float* __restrict__ pred, const float* __restrict__ gt,
    float* __restrict__ partial)
{
    __shared__ float gbuf[2][RROWS + 2][PADW];   // 5760 B; row 0 = y0-1

    const int ytile = blockIdx.x >> 2;
    const int xtile = blockIdx.x & 3;
    const int half  = blockIdx.y;
    const int b     = blockIdx.z;
    const int t0    = half * 4;
    const int tend  = t0 + (half ? 3 : 4);
    const int y0    = ytile * RROWS;
    const int x0    = xtile * XW;
    const int tid   = threadIdx.x;
    const size_t fs = (size_t)3 * FRAME_PIX;
    const float* pb = pred + (size_t)b * TT * fs;
    const float* gb = gt   + (size_t)b * TT * fs;

    // compute mapping: row r (0..7), 4 px at col cx (0..60)
    const int r  = tid >> 4;
    const int cx = (tid & 15) * 4;
    const size_t coff = (size_t)(y0 + r) * WW + (x0 + cx);

    // "extra" staging role: tid<64 -> halo rows; 64..103 -> side pads
    bool e_act = false, e_val = false;
    int  e_img = 0;
    size_t e_off = 0;
    float* e_dst = &gbuf[0][0][0];
    if (tid < 64) {
        e_act = true;
        e_img = tid >> 5;
        const int rsel = (tid >> 4) & 1;
        const int ec   = (tid & 15) * 4;
        const int ey   = rsel ? (y0 + RROWS) : (y0 - 1);
        e_val = (unsigned)ey < HH;
        e_off = e_val ? ((size_t)ey * WW + x0 + ec) : 0;
        e_dst = &gbuf[e_img][rsel ? RROWS + 1 : 0][4 + ec];
    } else if (tid < 104) {
        const int j = tid - 64;
        e_act = true;
        e_img = j / 20;
        const int rem  = j % 20;
        const int side = rem / 10;
        const int prow = rem % 10;
        const int ey = y0 - 1 + prow;
        const int ex = side ? (x0 + XW) : (x0 - 4);
        e_val = ((unsigned)ey < HH) && ((unsigned)ex < WW);
        e_off = e_val ? ((size_t)ey * WW + ex) : 0;
        e_dst = &gbuf[e_img][prow][side ? 4 + XW : 0];
    }

    float4 g1c[3];   // gt frame-t channels at this thread's 4 px (for mm)

    // ---- Prologue: stage gray of frame t0 (center + halo), keep g1c ----
    {
        const float* p1 = pb + (size_t)t0 * fs;
        const float* g1 = gb + (size_t)t0 * fs;
        const float4 pr  = ld4(p1 + coff);
        const float4 pg  = ld4(p1 + coff + FRAME_PIX);
        const float4 pbl = ld4(p1 + coff + 2 * FRAME_PIX);
        g1c[0] = ld4(g1 + coff);
        g1c[1] = ld4(g1 + coff + FRAME_PIX);
        g1c[2] = ld4(g1 + coff + 2 * FRAME_PIX);
        const float* eb = e_img ? g1 : p1;
        float4 x0v = make_float4(0.f,0.f,0.f,0.f), x1v = x0v, x2v = x0v;
        if (e_act && e_val) {
            x0v = ld4(eb + e_off);
            x1v = ld4(eb + e_off + FRAME_PIX);
            x2v = ld4(eb + e_off + 2 * FRAME_PIX);
        }
        st4(&gbuf[0][r + 1][4 + cx], gray4(pr, pg, pbl));
        st4(&gbuf[1][r + 1][4 + cx], gray4(g1c[0], g1c[1], g1c[2]));
        if (e_act) st4(e_dst, gray4(x0v, x1v, x2v));
    }
    __syncthreads();

    float s = 0.f;
    for (int t = t0; t < tend; ++t) {
        const float* p2 = pb + (size_t)(t + 1) * fs;
        const float* g2 = gb + (size_t)(t + 1) * fs;

        // Load frame t+1 (center channels + halo extras), all independent
        float4 p2c[3], g2c[3], ecur[3];
        p2c[0] = ld4(p2 + coff);
        p2c[1] = ld4(p2 + coff + FRAME_PIX);
        p2c[2] = ld4(p2 + coff + 2 * FRAME_PIX);
        g2c[0] = ld4(g2 + coff);
        g2c[1] = ld4(g2 + coff + FRAME_PIX);
        g2c[2] = ld4(g2 + coff + 2 * FRAME_PIX);
        const float* eb = e_img ? g2 : p2;
        ecur[0] = make_float4(0.f,0.f,0.f,0.f); ecur[1] = ecur[0]; ecur[2] = ecur[0];
        if (e_act && e_val) {
            ecur[0] = ld4(eb + e_off);
            ecur[1] = ld4(eb + e_off + FRAME_PIX);
            ecur[2] = ld4(eb + e_off + 2 * FRAME_PIX);
        }

        const float4 gp2 = gray4(p2c[0], p2c[1], p2c[2]);
        const float4 gg2 = gray4(g2c[0], g2c[1], g2c[2]);

        float mm[4];
        mm[0] = (fabsf(g2c[0].x - g1c[0].x) + fabsf(g2c[1].x - g1c[1].x) + fabsf(g2c[2].x - g1c[2].x)) * (1.f/3.f);
        mm[1] = (fabsf(g2c[0].y - g1c[0].y) + fabsf(g2c[1].y - g1c[1].y) + fabsf(g2c[2].y - g1c[2].y)) * (1.f/3.f);
        mm[2] = (fabsf(g2c[0].z - g1c[0].z) + fabsf(g2c[1].z - g1c[1].z) + fabsf(g2c[2].z - g1c[2].z)) * (1.f/3.f);
        mm[3] = (fabsf(g2c[0].w - g1c[0].w) + fabsf(g2c[1].w - g1c[1].w) + fabsf(g2c[2].w - g1c[2].w)) * (1.f/3.f);

        // Pair-t compute: Sobel on gray(t) in LDS, It vs gray(t+1) in regs
        float up[4], vp[4];
        #pragma unroll
        for (int img = 0; img < 2; ++img) {
            // padded floats cx+3..cx+8 -> aligned float4s at cx, cx+4, cx+8
            float w0[6], w1[6], w2[6];
            {
                const float* p = &gbuf[img][r][cx];
                const float4 A = ld4(p), B = ld4(p + 4), C = ld4(p + 8);
                w0[0] = A.w; w0[1] = B.x; w0[2] = B.y; w0[3] = B.z; w0[4] = B.w; w0[5] = C.x;
            }
            {
                const float* p = &gbuf[img][r + 1][cx];
                const float4 A = ld4(p), B = ld4(p + 4), C = ld4(p + 8);
                w1[0] = A.w; w1[1] = B.x; w1[2] = B.y; w1[3] = B.z; w1[4] = B.w; w1[5] = C.x;
            }
            {
                const float* p = &gbuf[img][r + 2][cx];
                const float4 A = ld4(p), B = ld4(p + 4), C = ld4(p + 8);
                w2[0] = A.w; w2[1] = B.x; w2[2] = B.y; w2[3] = B.z; w2[4] = B.w; w2[5] = C.x;
            }
            const float4 gr2 = img ? gg2 : gp2;
            const float g2a[4] = {gr2.x, gr2.y, gr2.z, gr2.w};
            #pragma unroll
            for (int j = 0; j < 4; ++j) {
                const float Ix = (w0[j] - w0[j + 2]) + 2.0f * (w1[j] - w1[j + 2]) + (w2[j] - w2[j + 2]);
                const float Iy = (w0[j] + 2.0f * w0[j + 1] + w0[j + 2])
                               - (w2[j] + 2.0f * w2[j + 1] + w2[j + 2]);
                const float It = g2a[j] - w1[j + 1];
                const float inv = 1.0f / (Ix * Ix + Iy * Iy + EPS);
                if (img == 0) {
                    up[j] = -(Ix * It) * inv;
                    vp[j] = -(Iy * It) * inv;
                } else {
                    s += (fabsf(up[j] + (Ix * It) * inv) + fabsf(vp[j] + (Iy * It) * inv)) * mm[j];
                }
            }
        }

        if (t + 1 < tend) {
            __syncthreads();
            // Rotate: gray(t+1) into LDS; carry gt channels for next mm
            st4(&gbuf[0][r + 1][4 + cx], gp2);
            st4(&gbuf[1][r + 1][4 + cx], gg2);
            if (e_act) st4(e_dst, gray4(ecur[0], ecur[1], ecur[2]));
            g1c[0] = g2c[0]; g1c[1] = g2c[1]; g1c[2] = g2c[2];
            __syncthreads();
        }
    }

    // ---- Block reduction (2 waves) -> one partial per block ----
    #pragma unroll
    for (int off = 32; off > 0; off >>= 1) s += __shfl_down(s, off, 64);

    __shared__ float wsum[2];
    if ((tid & 63) == 0) wsum[tid >> 6] = s;
    __syncthreads();
    if (tid == 0) {
        partial[(b * 2 + half) * (NYT * NXT) + blockIdx.x] = wsum[0] + wsum[1];
    }
}

__global__ __launch_bounds__(256) void reduce_kernel(
    const float* __restrict__ partial, float* __restrict__ out)
{
    const int i = threadIdx.x;
    const float4 v0 = ld4(partial + i * 8);
    const float4 v1 = ld4(partial + i * 8 + 4);    // 2048 floats total
    float s = ((v0.x + v0.y) + (v0.z + v0.w)) + ((v1.x + v1.y) + (v1.z + v1.w));
    #pragma unroll
    for (int off = 32; off > 0; off >>= 1) s += __shfl_down(s, off, 64);

    __shared__ float wsum[4];
    if ((i & 63) == 0) wsum[i >> 6] = s;
    __syncthreads();
    if (i == 0) {
        out[0] = ((wsum[0] + wsum[1]) + (wsum[2] + wsum[3])) * INV_N;
    }
}

extern "C" void kernel_launch(void* const* d_in, const int* in_sizes, int n_in,
                              void* d_out, int out_size, void* d_ws, size_t ws_size,
                              hipStream_t stream) {
    const float* pred = (const float*)d_in[0];
    const float* gt   = (const float*)d_in[1];
    float* partial    = (float*)d_ws;     // NBLK floats = 8192 B
    float* out        = (float*)d_out;

    dim3 grid(NYT * NXT, 2, BB);          // (128, 2, 8) = 2048 blocks
    dim3 block(128);
    flow_loss_kernel<<<grid, block, 0, stream>>>(pred, gt, partial);
    reduce_kernel<<<1, 256, 0, stream>>>(partial, out);
}